// Round 1
// baseline (449.558 us; speedup 1.0000x reference)
//
#include <hip/hip_runtime.h>
#include <stdint.h>

#define B_ 64
#define T_ 4096
#define D_ 90
#define K_ 32
#define C_ 64   // number of T-chunks (chunk length = 64)

typedef float f32x16 __attribute__((ext_vector_type(16)));
typedef __bf16 bf16x8 __attribute__((ext_vector_type(8)));

// ---- workspace layout (float offsets). total 12593920 floats = 50.4 MB ----
#define WS_A     0          // 1024 : softmax(transition) rows, A[j*32+k]
#define WS_PI    1024       // 32   : softmax(priors)
#define WS_C0    1056       // 32   : per-state emission constant
#define WS_MSUM  1088       // 64   : sum_t max_k em[b,t,k] (atomic)
#define WS_C2    1152       // 5760 : 2880 float2 (-0.5*iv, mu*iv) laid out [d][k]
#define WS_EACC  6912       // 4096 ints : per-(b,chunk) renorm exponent
#define WS_E     11008      // 8388608 : E[b][t][k] = exp(em - m_t)
#define WS_Q     8399616    // 4194304 : Q[b][c][k_new][j_old]

// block-swap involution: swap 4-7<->8-11 and 20-23<->24-27
__device__ __forceinline__ int perm_r(int r) {
  int t2 = (r >> 2) & 3;
  return r + ((t2 == 1) ? 4 : (t2 == 2) ? -4 : 0);
}
// pack two f32 -> bf16x2 dword (truncation; error budget is huge here)
__device__ __forceinline__ uint32_t pk2(float hi, float lo) {
  return (__float_as_uint(hi) & 0xFFFF0000u) | (__float_as_uint(lo) >> 16);
}
__device__ __forceinline__ bf16x8 mkbf(uint32_t a, uint32_t b, uint32_t c, uint32_t d) {
  union { uint32_t u[4]; bf16x8 v; } x;
  x.u[0] = a; x.u[1] = b; x.u[2] = c; x.u[3] = d;
  return x.v;
}

// ---------------- prep: softmaxes + emission constants ----------------
__global__ __launch_bounds__(1024) void prep_kernel(
    const float* __restrict__ priors, const float* __restrict__ trans,
    const float* __restrict__ mu, const float* __restrict__ lv,
    float* __restrict__ ws) {
  int tid = threadIdx.x;
  {  // transition row softmax: tid = j*32+k, 32-lane groups are rows
    float v = trans[tid];
    float m = v;
    #pragma unroll
    for (int mk = 16; mk; mk >>= 1) m = fmaxf(m, __shfl_xor(m, mk));
    float e = expf(v - m);
    float s = e;
    #pragma unroll
    for (int mk = 16; mk; mk >>= 1) s += __shfl_xor(s, mk);
    ws[WS_A + tid] = e / s;
  }
  if (tid < 32) {  // prior softmax
    float v = priors[tid];
    float m = v;
    #pragma unroll
    for (int mk = 16; mk; mk >>= 1) m = fmaxf(m, __shfl_xor(m, mk));
    float e = expf(v - m);
    float s = e;
    #pragma unroll
    for (int mk = 16; mk; mk >>= 1) s += __shfl_xor(s, mk);
    ws[WS_PI + tid] = e / s;
  }
  for (int i = tid; i < D_ * K_; i += 1024) {  // [d][k] float2 consts
    int d = i >> 5, k = i & 31;
    float l  = lv[k * D_ + d];
    float iv = expf(-l);
    ws[WS_C2 + 2 * i]     = -0.5f * iv;
    ws[WS_C2 + 2 * i + 1] = mu[k * D_ + d] * iv;
  }
  if (tid < 32) {  // c0[k] = -0.5*(sum mu^2*iv + sum lv + D*log(2pi))
    float s = 0.0f;
    for (int d = 0; d < D_; ++d) {
      float l  = lv[tid * D_ + d];
      float iv = expf(-l);
      float m_ = mu[tid * D_ + d];
      s += m_ * m_ * iv + l;
    }
    ws[WS_C0 + tid] = -0.5f * (s + (float)D_ * 1.8378770664093453f);
  }
}

// ---------------- emission: E[b][t][k] = exp(em - max_k em), Msum[b] += max ----
__global__ __launch_bounds__(512) void emis_kernel(const float* __restrict__ X,
                                                   float* __restrict__ ws) {
  __shared__ float2 c2l[D_ * K_];
  __shared__ float  xs[16 * D_];
  __shared__ float  marr[16];
  int tid = threadIdx.x;
  int b   = blockIdx.x >> 8;          // 256 tiles of 16 t's per b
  int t0  = (blockIdx.x & 255) << 4;
  const float2* c2g = (const float2*)(ws + WS_C2);
  for (int i = tid; i < D_ * K_; i += 512) c2l[i] = c2g[i];
  const float* xg = X + ((size_t)b * T_ + t0) * D_;
  for (int i = tid; i < 16 * D_; i += 512) xs[i] = xg[i];
  __syncthreads();
  int g = tid >> 5, k = tid & 31;     // group g handles t = t0+g, lane = state k
  float em = ws[WS_C0 + k];
  const float* xrow = xs + g * D_;
  #pragma unroll 6
  for (int d = 0; d < D_; ++d) {
    float  x  = xrow[d];              // broadcast read
    float2 ab = c2l[d * K_ + k];      // ds_read_b64, conflict-free
    em = fmaf(x, fmaf(x, ab.x, ab.y), em);
  }
  float m = em;
  #pragma unroll
  for (int mk = 16; mk; mk >>= 1) m = fmaxf(m, __shfl_xor(m, mk));
  int t = t0 + g;
  ws[WS_E + ((size_t)b * T_ + t) * K_ + k] = exp2f((em - m) * 1.44269504088896f);
  if (k == 0) marr[g] = m;
  __syncthreads();
  if (tid == 0) {
    float s = 0.0f;
    #pragma unroll
    for (int i = 0; i < 16; ++i) s += marr[i];
    atomicAdd(ws + WS_MSUM + b, s);
  }
}

// ---------------- phase 1: per-(b,chunk) transfer matrix via MFMA ----------------
// Maintains Q = P^T in B-operand layout; Q' = G^T x Q with pi folded into static
// A-fragment so that D registers repack directly (in-lane) into next B-fragment.
__global__ __launch_bounds__(64) void chunk_kernel(float* __restrict__ ws) {
  int l = threadIdx.x;
  int h = l >> 5, n = l & 31;
  int bc = blockIdx.x;
  int b = bc >> 6, c = bc & 63;
  int col = perm_r(n);                // logical output-state of this lane's A column
  const float* A = ws + WS_A;
  float astat[16];                    // A[s][col] for s = 8h+j and 16+8h+j
  #pragma unroll
  for (int j = 0; j < 8; ++j) {
    astat[j]     = A[(8 * h + j) * K_ + col];
    astat[8 + j] = A[(16 + 8 * h + j) * K_ + col];
  }
  uint32_t q[8];                      // Q fragments (bf16x2 dwords), init = I
  #pragma unroll
  for (int r = 0; r < 4; ++r) {
    int s0 = 8 * h + 2 * r;
    uint32_t lo = (s0 == n)     ? 0x3F80u : 0u;
    uint32_t hi = (s0 + 1 == n) ? 0x3F80u : 0u;
    q[r] = lo | (hi << 16);
    int s2 = s0 + 16;
    lo = (s2 == n)     ? 0x3F80u : 0u;
    hi = (s2 + 1 == n) ? 0x3F80u : 0u;
    q[4 + r] = lo | (hi << 16);
  }
  int tbeg = (c == 0) ? 1 : c * 64;   // t=0 is the prior step, no transition
  int tend = c * 64 + 64;
  const float* Eb = ws + WS_E + (size_t)b * T_ * K_ + col;
  float e0 = Eb[(size_t)tbeg * K_];
  int eacc = 0;
  f32x16 acc;
  #pragma unroll
  for (int r = 0; r < 16; ++r) acc[r] = 0.0f;
  for (int t = tbeg; t < tend; ++t) {
    int tn = (t + 1 < tend) ? (t + 1) : t;
    float e1 = Eb[(size_t)tn * K_];   // prefetch next step's emission scale
    uint32_t au[8];
    #pragma unroll
    for (int r = 0; r < 4; ++r) {     // A-frag = astat * E[col], truncated to bf16
      au[r]     = pk2(astat[2 * r + 1] * e0, astat[2 * r] * e0);
      au[4 + r] = pk2(astat[8 + 2 * r + 1] * e0, astat[8 + 2 * r] * e0);
    }
    bf16x8 alo = mkbf(au[0], au[1], au[2], au[3]);
    bf16x8 ahi = mkbf(au[4], au[5], au[6], au[7]);
    bf16x8 qlo = mkbf(q[0], q[1], q[2], q[3]);
    bf16x8 qhi = mkbf(q[4], q[5], q[6], q[7]);
    f32x16 z;
    #pragma unroll
    for (int r = 0; r < 16; ++r) z[r] = 0.0f;
    acc = __builtin_amdgcn_mfma_f32_32x32x16_bf16(alo, qlo, z, 0, 0, 0);
    acc = __builtin_amdgcn_mfma_f32_32x32x16_bf16(ahi, qhi, acc, 0, 0, 0);
    if ((t & 7) == 7) {               // exact power-of-2 renormalization
      float m = acc[0];
      #pragma unroll
      for (int r = 1; r < 16; ++r) m = fmaxf(m, acc[r]);
      #pragma unroll
      for (int mk = 1; mk <= 32; mk <<= 1) m = fmaxf(m, __shfl_xor(m, mk));
      int ex;
      frexpf(m, &ex);
      float sc = ldexpf(1.0f, -ex);
      eacc += ex;
      #pragma unroll
      for (int r = 0; r < 16; ++r) acc[r] *= sc;
    }
    #pragma unroll
    for (int r = 0; r < 4; ++r) {     // D regs -> next B-frag, in-lane repack only
      q[r]     = pk2(acc[2 * r + 1], acc[2 * r]);
      q[4 + r] = pk2(acc[8 + 2 * r + 1], acc[8 + 2 * r]);
    }
    e0 = e1;
  }
  float* Qout = ws + WS_Q + (size_t)bc * (K_ * K_);
  #pragma unroll
  for (int r = 0; r < 16; ++r) {      // store un-permuted: row = pi(physical row)
    int m_ = (r & 3) + 8 * (r >> 2) + 4 * h;
    Qout[perm_r(m_) * K_ + n] = acc[r];
  }
  if (l == 0) ((int*)ws)[WS_EACC + bc] = eacc;
}

// ---------------- phase 2: sequential combine of 64 chunk matrices per b ----------------
__global__ __launch_bounds__(64) void combine_kernel(float* __restrict__ ws,
                                                     float* __restrict__ out) {
  __shared__ float qs[K_ * 33];
  int lane = threadIdx.x;
  int b = blockIdx.x;
  float alpha = 0.0f;
  if (lane < 32) alpha = ws[WS_PI + lane] * ws[WS_E + (size_t)b * T_ * K_ + lane];
  int escale = 0;
  const int* eaccs = ((const int*)ws) + WS_EACC + b * C_;
  for (int c = 0; c < C_; ++c) {
    const float* Qc = ws + WS_Q + ((size_t)(b * C_ + c)) * (K_ * K_);
    #pragma unroll
    for (int p = 0; p < 16; ++p) {    // stage 1024 floats coalesced -> LDS (+pad)
      int i = lane + p * 64;
      qs[(i >> 5) * 33 + (i & 31)] = Qc[i];
    }
    __syncthreads();
    if (lane < 32) {                  // alpha'[k] = sum_j alpha[j] * Q[k][j]
      float s = 0.0f;
      #pragma unroll 8
      for (int j = 0; j < 32; ++j) {
        float aj = __shfl(alpha, j);
        s = fmaf(aj, qs[lane * 33 + j], s);
      }
      float m = s;
      #pragma unroll
      for (int mk = 16; mk; mk >>= 1) m = fmaxf(m, __shfl_xor(m, mk));
      int ex;
      frexpf(m, &ex);
      alpha = ldexpf(s, -ex);
      escale += ex;
    }
    escale += eaccs[c];
    __syncthreads();
  }
  if (lane < 32) {
    float ssum = alpha;
    #pragma unroll
    for (int mk = 16; mk; mk >>= 1) ssum += __shfl_xor(ssum, mk);
    if (lane == 0) {
      float res = logf(ssum) + (float)escale * 0.69314718055994531f + ws[WS_MSUM + b];
      atomicAdd(out, res);
    }
  }
}

extern "C" void kernel_launch(void* const* d_in, const int* in_sizes, int n_in,
                              void* d_out, int out_size, void* d_ws, size_t ws_size,
                              hipStream_t stream) {
  (void)in_sizes; (void)n_in; (void)out_size; (void)ws_size;
  const float* X      = (const float*)d_in[0];
  const float* priors = (const float*)d_in[1];
  const float* trans  = (const float*)d_in[2];
  const float* mu     = (const float*)d_in[3];
  const float* lv     = (const float*)d_in[4];
  float* ws  = (float*)d_ws;
  float* out = (float*)d_out;
  hipMemsetAsync(out, 0, sizeof(float), stream);
  hipMemsetAsync(ws + WS_MSUM, 0, B_ * sizeof(float), stream);
  prep_kernel<<<1, 1024, 0, stream>>>(priors, trans, mu, lv, ws);
  emis_kernel<<<B_ * (T_ / 16), 512, 0, stream>>>(X, ws);
  chunk_kernel<<<B_ * C_, 64, 0, stream>>>(ws);
  combine_kernel<<<B_, 64, 0, stream>>>(ws, out);
}

// Round 2
// 330.985 us; speedup vs baseline: 1.3582x; 1.3582x over previous
//
#include <hip/hip_runtime.h>
#include <stdint.h>

#define B_ 64
#define T_ 4096
#define D_ 90
#define K_ 32
#define C_ 64   // number of T-chunks (chunk length = 64)

typedef float f32x16 __attribute__((ext_vector_type(16)));
typedef __bf16 bf16x8 __attribute__((ext_vector_type(8)));

// ---- workspace layout (float offsets). total ~8396928 floats = 33.6 MB ----
#define WS_A     0          // 1024 : softmax(transition) rows, A[j*32+k]
#define WS_PI    1024       // 32   : softmax(priors)
#define WS_C0    1056       // 32   : per-state emission constant
#define WS_MSUM  1088       // 64   : sum_t max_k em[b,t,k] (atomic)
#define WS_EACC  1152       // 4096 ints : per-(b,chunk) renorm exponent
#define WS_WF    5248       // 6144 bf16 : MFMA B-fragments of emission weights
#define WS_E     8320       // 8388608 bf16 : E^T[b][k][t] = exp(em - m_t)
#define WS_Q     4202624    // 4194304 : Q[b][c][k_new][j_old]

// block-swap involution: swap 4-7<->8-11 and 20-23<->24-27
__device__ __forceinline__ int perm_r(int r) {
  int t2 = (r >> 2) & 3;
  return r + ((t2 == 1) ? 4 : (t2 == 2) ? -4 : 0);
}
// pack two f32 -> bf16x2 dword (truncation; used in chunk recursion)
__device__ __forceinline__ uint32_t pk2(float hi, float lo) {
  return (__float_as_uint(hi) & 0xFFFF0000u) | (__float_as_uint(lo) >> 16);
}
// pack two f32 -> bf16x2 dword with round-to-nearest (emission path)
__device__ __forceinline__ uint32_t rnd_pk(float hi, float lo) {
  uint32_t uh = __float_as_uint(hi) + 0x8000u;
  uint32_t ul = __float_as_uint(lo) + 0x8000u;
  return (uh & 0xFFFF0000u) | (ul >> 16);
}
__device__ __forceinline__ float bf2f(ushort u) {
  return __uint_as_float(((uint32_t)u) << 16);
}
__device__ __forceinline__ bf16x8 mkbf(uint32_t a, uint32_t b, uint32_t c, uint32_t d) {
  union { uint32_t u[4]; bf16x8 v; } x;
  x.u[0] = a; x.u[1] = b; x.u[2] = c; x.u[3] = d;
  return x.v;
}

// ---------------- prep: softmaxes + emission weight fragments ----------------
__global__ __launch_bounds__(1024) void prep_kernel(
    const float* __restrict__ priors, const float* __restrict__ trans,
    const float* __restrict__ mu, const float* __restrict__ lv,
    float* __restrict__ ws) {
  int tid = threadIdx.x;
  {  // transition row softmax: tid = j*32+k, 32-lane groups are rows
    float v = trans[tid];
    float m = v;
    #pragma unroll
    for (int mk = 16; mk; mk >>= 1) m = fmaxf(m, __shfl_xor(m, mk));
    float e = expf(v - m);
    float s = e;
    #pragma unroll
    for (int mk = 16; mk; mk >>= 1) s += __shfl_xor(s, mk);
    ws[WS_A + tid] = e / s;
  }
  if (tid < 32) {  // prior softmax
    float v = priors[tid];
    float m = v;
    #pragma unroll
    for (int mk = 16; mk; mk >>= 1) m = fmaxf(m, __shfl_xor(m, mk));
    float e = expf(v - m);
    float s = e;
    #pragma unroll
    for (int mk = 16; mk; mk >>= 1) s += __shfl_xor(s, mk);
    ws[WS_PI + tid] = e / s;
  }
  // MFMA B-operand weight fragments, bf16, layout [c][mat][lane][j]
  // element = W[d = 16c + 8(lane>>5) + j][k = lane&31]; mat0 = -0.5*iv (x^2), mat1 = mu*iv (x)
  for (int i = tid; i < 6144; i += 1024) {
    int j = i & 7, l = (i >> 3) & 63, cm = i >> 9;
    int c = cm >> 1, mat = cm & 1;
    int h = l >> 5, nn = l & 31;
    int d = 16 * c + 8 * h + j;
    float v = 0.0f;
    if (d < D_) {
      float ivd = expf(-lv[nn * D_ + d]);
      v = (mat == 0) ? -0.5f * ivd : mu[nn * D_ + d] * ivd;
    }
    ((ushort*)(ws + WS_WF))[i] = (ushort)((__float_as_uint(v) + 0x8000u) >> 16);
  }
  if (tid < 32) {  // c0[k] = -0.5*(sum mu^2*iv + sum lv + D*log(2pi))
    float s = 0.0f;
    for (int d = 0; d < D_; ++d) {
      float l  = lv[tid * D_ + d];
      float iv = expf(-l);
      float m_ = mu[tid * D_ + d];
      s += m_ * m_ * iv + l;
    }
    ws[WS_C0 + tid] = -0.5f * (s + (float)D_ * 1.8378770664093453f);
  }
}

// ---------------- emission via MFMA: E^T[b][k][t] = exp(em - m_t) (bf16) ----------------
// em[t,k] = x2 @ W2 + x @ W1 + c0 : per-wave 32-t tile, 12 mfma_32x32x16_bf16.
__global__ __launch_bounds__(256) void emis_kernel(const float* __restrict__ X,
                                                   float* __restrict__ ws) {
  int l = threadIdx.x & 63;
  int n = l & 31, h = l >> 5;
  int wv = (blockIdx.x << 2) + (threadIdx.x >> 6);   // tile id 0..8191
  int t0 = wv << 5;
  int b  = t0 >> 12;
  const uint4* wfp = (const uint4*)((const ushort*)(ws + WS_WF));
  uint4 wf[12];
  #pragma unroll
  for (int cm = 0; cm < 12; ++cm) wf[cm] = wfp[cm * 64 + l];   // coalesced b128
  float c0 = ws[WS_C0 + n];
  const float* Xrow = X + (size_t)(t0 + n) * D_;    // A-row m = n = lane&31
  f32x16 acc1, acc2;
  #pragma unroll
  for (int r = 0; r < 16; ++r) { acc1[r] = 0.0f; acc2[r] = 0.0f; }
  #pragma unroll
  for (int c = 0; c < 6; ++c) {
    float x[8];
    int s = 16 * c + 8 * h;                          // kk = d = s + j
    if (c < 5) {
      const float2* p = (const float2*)(Xrow + s);   // 8B-aligned (row stride 360B)
      #pragma unroll
      for (int r = 0; r < 4; ++r) { float2 v = p[r]; x[2*r] = v.x; x[2*r+1] = v.y; }
    } else {                                         // d = 80..95, pad >= 90 with 0
      #pragma unroll
      for (int j = 0; j < 8; ++j) x[j] = (s + j < D_) ? Xrow[s + j] : 0.0f;
    }
    union { uint32_t u[4]; bf16x8 v; } xb, x2b;
    #pragma unroll
    for (int r = 0; r < 4; ++r) {
      xb.u[r]  = rnd_pk(x[2*r+1], x[2*r]);
      x2b.u[r] = rnd_pk(x[2*r+1] * x[2*r+1], x[2*r] * x[2*r]);
    }
    union { uint4 u; bf16x8 v; } w2, w1;
    w2.u = wf[c * 2]; w1.u = wf[c * 2 + 1];
    acc1 = __builtin_amdgcn_mfma_f32_32x32x16_bf16(xb.v,  w1.v, acc1, 0, 0, 0);
    acc2 = __builtin_amdgcn_mfma_f32_32x32x16_bf16(x2b.v, w2.v, acc2, 0, 0, 0);
  }
  // C/D: col k = n, row t = (r&3) + 8*(r>>2) + 4*h
  float em[16], mrow[16];
  #pragma unroll
  for (int r = 0; r < 16; ++r) {
    float v = acc1[r] + acc2[r] + c0;
    em[r] = v;
    float m = v;
    #pragma unroll
    for (int mk = 1; mk <= 16; mk <<= 1) m = fmaxf(m, __shfl_xor(m, mk));  // max over k
    mrow[r] = m;
  }
  ushort* Ew = (ushort*)(ws + WS_E);
  size_t ebase = (size_t)(b * K_ + n) * T_ + (t0 & (T_ - 1));
  #pragma unroll
  for (int q = 0; q < 4; ++q) {  // regs 4q..4q+3 are consecutive t's: pack 4 bf16 -> 8B store
    float e0 = exp2f((em[4*q]   - mrow[4*q])   * 1.44269504088896f);
    float e1 = exp2f((em[4*q+1] - mrow[4*q+1]) * 1.44269504088896f);
    float e2 = exp2f((em[4*q+2] - mrow[4*q+2]) * 1.44269504088896f);
    float e3 = exp2f((em[4*q+3] - mrow[4*q+3]) * 1.44269504088896f);
    uint2 d;
    d.x = rnd_pk(e1, e0);
    d.y = rnd_pk(e3, e2);
    *(uint2*)(Ew + ebase + 8 * q + 4 * h) = d;
  }
  float msum = 0.0f;
  #pragma unroll
  for (int r = 0; r < 16; ++r) msum += mrow[r];
  msum += __shfl_xor(msum, 32);                      // both halves' 16 rows
  if (l == 0) atomicAdd(ws + WS_MSUM + b, msum);
}

// ---------------- phase 1: per-(b,chunk) transfer matrix via MFMA ----------------
__global__ __launch_bounds__(64) void chunk_kernel(float* __restrict__ ws) {
  int l = threadIdx.x;
  int h = l >> 5, n = l & 31;
  int bc = blockIdx.x;
  int b = bc >> 6, c = bc & 63;
  int col = perm_r(n);                // logical output-state of this lane's A column
  const float* A = ws + WS_A;
  float astat[16];                    // A[s][col] for s = 8h+j and 16+8h+j
  #pragma unroll
  for (int j = 0; j < 8; ++j) {
    astat[j]     = A[(8 * h + j) * K_ + col];
    astat[8 + j] = A[(16 + 8 * h + j) * K_ + col];
  }
  uint32_t q[8];                      // Q fragments (bf16x2 dwords), init = I
  #pragma unroll
  for (int r = 0; r < 4; ++r) {
    int s0 = 8 * h + 2 * r;
    uint32_t lo = (s0 == n)     ? 0x3F80u : 0u;
    uint32_t hi = (s0 + 1 == n) ? 0x3F80u : 0u;
    q[r] = lo | (hi << 16);
    int s2 = s0 + 16;
    lo = (s2 == n)     ? 0x3F80u : 0u;
    hi = (s2 + 1 == n) ? 0x3F80u : 0u;
    q[4 + r] = lo | (hi << 16);
  }
  int tbeg = (c == 0) ? 1 : c * 64;   // t=0 is the prior step, no transition
  int tend = c * 64 + 64;
  const ushort* Eb = (const ushort*)(ws + WS_E) + (size_t)(b * K_ + col) * T_;
  float e0 = bf2f(Eb[tbeg]);
  int eacc = 0;
  f32x16 acc;
  #pragma unroll
  for (int r = 0; r < 16; ++r) acc[r] = 0.0f;
  for (int t = tbeg; t < tend; ++t) {
    int tn = (t + 1 < tend) ? (t + 1) : t;
    float e1 = bf2f(Eb[tn]);          // prefetch next step's emission scale
    uint32_t au[8];
    #pragma unroll
    for (int r = 0; r < 4; ++r) {     // A-frag = astat * E[col], truncated to bf16
      au[r]     = pk2(astat[2 * r + 1] * e0, astat[2 * r] * e0);
      au[4 + r] = pk2(astat[8 + 2 * r + 1] * e0, astat[8 + 2 * r] * e0);
    }
    bf16x8 alo = mkbf(au[0], au[1], au[2], au[3]);
    bf16x8 ahi = mkbf(au[4], au[5], au[6], au[7]);
    bf16x8 qlo = mkbf(q[0], q[1], q[2], q[3]);
    bf16x8 qhi = mkbf(q[4], q[5], q[6], q[7]);
    f32x16 z;
    #pragma unroll
    for (int r = 0; r < 16; ++r) z[r] = 0.0f;
    acc = __builtin_amdgcn_mfma_f32_32x32x16_bf16(alo, qlo, z, 0, 0, 0);
    acc = __builtin_amdgcn_mfma_f32_32x32x16_bf16(ahi, qhi, acc, 0, 0, 0);
    if ((t & 7) == 7) {               // exact power-of-2 renormalization
      float m = acc[0];
      #pragma unroll
      for (int r = 1; r < 16; ++r) m = fmaxf(m, acc[r]);
      #pragma unroll
      for (int mk = 1; mk <= 32; mk <<= 1) m = fmaxf(m, __shfl_xor(m, mk));
      int ex;
      frexpf(m, &ex);
      float sc = ldexpf(1.0f, -ex);
      eacc += ex;
      #pragma unroll
      for (int r = 0; r < 16; ++r) acc[r] *= sc;
    }
    #pragma unroll
    for (int r = 0; r < 4; ++r) {     // D regs -> next B-frag, in-lane repack only
      q[r]     = pk2(acc[2 * r + 1], acc[2 * r]);
      q[4 + r] = pk2(acc[8 + 2 * r + 1], acc[8 + 2 * r]);
    }
    e0 = e1;
  }
  float* Qout = ws + WS_Q + (size_t)bc * (K_ * K_);
  #pragma unroll
  for (int r = 0; r < 16; ++r) {      // store un-permuted: row = pi(physical row)
    int m_ = (r & 3) + 8 * (r >> 2) + 4 * h;
    Qout[perm_r(m_) * K_ + n] = acc[r];
  }
  if (l == 0) ((int*)ws)[WS_EACC + bc] = eacc;
}

// ---------------- phase 2: sequential combine of 64 chunk matrices per b ----------------
// lane 2k+half holds Q[k][16*half .. +15] in registers; depth-2 global prefetch.
__global__ __launch_bounds__(64) void combine_kernel(float* __restrict__ ws,
                                                     float* __restrict__ out) {
  int l = threadIdx.x;
  int b = blockIdx.x;
  int half = l & 1;
  const ushort* Ew = (const ushort*)(ws + WS_E);
  float alpha = 0.0f;
  if (l < 32) alpha = ws[WS_PI + l] * bf2f(Ew[(size_t)(b * K_ + l) * T_]);
  int escale = 0;
  const int* eaccs = ((const int*)ws) + WS_EACC + b * C_;
  const float4* Qb = (const float4*)(ws + WS_Q + (size_t)b * (C_ * K_ * K_));
  float4 buf[2][4];
  #pragma unroll
  for (int i = 0; i < 4; ++i) buf[0][i] = Qb[0 * 256 + l * 4 + i];
  #pragma unroll
  for (int i = 0; i < 4; ++i) buf[1][i] = Qb[1 * 256 + l * 4 + i];
  for (int c = 0; c < C_; ++c) {
    int pb = c & 1;
    float s = 0.0f;
    #pragma unroll
    for (int i = 0; i < 16; ++i) {     // alpha'[k] = sum_j alpha[j] * Q[k][j]
      float aj = __shfl(alpha, 16 * half + i);
      s = fmaf(aj, ((const float*)&buf[pb][0])[i], s);
    }
    if (c + 2 < C_) {                  // depth-2 prefetch into the buffer just consumed
      #pragma unroll
      for (int i = 0; i < 4; ++i) buf[pb][i] = Qb[(c + 2) * 256 + l * 4 + i];
    }
    s += __shfl_xor(s, 1);             // combine j-halves: lanes 2k,2k+1 hold alpha'[k]
    float mm = s;
    #pragma unroll
    for (int mk = 2; mk <= 32; mk <<= 1) mm = fmaxf(mm, __shfl_xor(mm, mk));
    int ex;
    frexpf(mm, &ex);
    s = ldexpf(s, -ex);
    escale += ex + eaccs[c];
    alpha = __shfl(s, (l & 31) * 2);   // lane j <- alpha'[j]
  }
  if (l < 32) {
    float ssum = alpha;
    #pragma unroll
    for (int mk = 16; mk; mk >>= 1) ssum += __shfl_xor(ssum, mk);
    if (l == 0) {
      float res = logf(ssum) + (float)escale * 0.69314718055994531f + ws[WS_MSUM + b];
      atomicAdd(out, res);
    }
  }
}

extern "C" void kernel_launch(void* const* d_in, const int* in_sizes, int n_in,
                              void* d_out, int out_size, void* d_ws, size_t ws_size,
                              hipStream_t stream) {
  (void)in_sizes; (void)n_in; (void)out_size; (void)ws_size;
  const float* X      = (const float*)d_in[0];
  const float* priors = (const float*)d_in[1];
  const float* trans  = (const float*)d_in[2];
  const float* mu     = (const float*)d_in[3];
  const float* lv     = (const float*)d_in[4];
  float* ws  = (float*)d_ws;
  float* out = (float*)d_out;
  hipMemsetAsync(out, 0, sizeof(float), stream);
  hipMemsetAsync(ws + WS_MSUM, 0, B_ * sizeof(float), stream);
  prep_kernel<<<1, 1024, 0, stream>>>(priors, trans, mu, lv, ws);
  emis_kernel<<<2048, 256, 0, stream>>>(X, ws);
  chunk_kernel<<<B_ * C_, 64, 0, stream>>>(ws);
  combine_kernel<<<B_, 64, 0, stream>>>(ws, out);
}